// Round 5
// baseline (969.624 us; speedup 1.0000x reference)
//
#include <hip/hip_runtime.h>
#include <hip/hip_fp16.h>

// APPNP: K steps of D^{-1/2} A D^{-1/2} propagation + teleport, then MFMA MLP.
// R16: feature-split propagation. h is stored as TWO slabs of 64 halfs
// (128 B, sector-aligned rows): feats 0..63 and 64..99 (+pad). Each step
// propagates both slabs in ONE launch (blockIdx.y = slab); per-pass gather
// footprint = 12.8 MB (vs 25.6), so within-step retouches survive the 4 MB
// per-XCD L2 far better -> L2-miss (FETCH) traffic drops. Gathers pack 2
// edges per instruction (lanes 0-31 / 32-63), 4 cache-line requests per
// instruction = same TA behavior as the proven R14 pattern; same total
// instruction count. R15's 200B packed rows are dropped (128B-sector
// misalignment RAISED fetch 112->131 MB). CSR build / MFMA MLP unchanged.

#define N_NODES 100000
#define N_PAD   100032   // rows allocated per layout (zero rows + MLP slack)
#define N_EDGES 800000
#define D_DATA  100
#define H_DIM   256
#define N_CLS   47
#define K_STEPS 10
#define ALPHA   0.1f
#define HS      128      // fp16 row stride (halfs) of the MLP input layout
#define SH      64       // fp16 row stride (halfs) of one feature slab
#define MB      64       // nodes per MLP block

#define SLAB_HALFS ((size_t)N_PAD * SH)   // one slab; slab pair is contiguous

#define SCAN_NB    200
#define SCAN_CHUNK 500   // 200*500 == N_NODES
#define EW_CAP (N_EDGES + 7 * N_NODES)   // degrees padded to multiple of 8

typedef _Float16 half8_t __attribute__((ext_vector_type(8)));
typedef float floatx4 __attribute__((ext_vector_type(4)));

// ---------------- CSR build ----------------

// histogram + per-edge slot (within-dst rank; order irrelevant, weights are 1)
__global__ void deg_kernel(const int* __restrict__ dst, int* __restrict__ deg,
                           int* __restrict__ slot, int e) {
    int i = blockIdx.x * blockDim.x + threadIdx.x;
    if (i < e) slot[i] = atomicAdd(&deg[dst[i]], 1);
}

__global__ __launch_bounds__(256) void scan_partial_kernel(
        const int* __restrict__ deg, int* __restrict__ partials) {
    __shared__ int red[256];
    int t = threadIdx.x;
    int base = blockIdx.x * SCAN_CHUNK;
    int s = 0;
    int i0 = 2 * t, i1 = 2 * t + 1;
    if (i0 < SCAN_CHUNK) s += (deg[base + i0] + 7) & ~7;
    if (i1 < SCAN_CHUNK) s += (deg[base + i1] + 7) & ~7;
    red[t] = s;
    __syncthreads();
    for (int off = 128; off > 0; off >>= 1) {
        if (t < off) red[t] += red[t + off];
        __syncthreads();
    }
    if (t == 0) partials[blockIdx.x] = red[0];
}

__global__ __launch_bounds__(256) void scan_top_kernel(
        const int* __restrict__ partials, int* __restrict__ pofs,
        int* __restrict__ row_ptr) {
    __shared__ int s[256];
    int t = threadIdx.x;
    s[t] = (t < SCAN_NB) ? partials[t] : 0;
    __syncthreads();
    for (int off = 1; off < 256; off <<= 1) {
        int v = (t >= off) ? s[t - off] : 0;
        __syncthreads();
        s[t] += v;
        __syncthreads();
    }
    if (t < SCAN_NB) pofs[t] = s[t] - partials[t];
    if (t == SCAN_NB - 1) row_ptr[N_NODES] = s[t];   // padded total
}

__global__ __launch_bounds__(256) void scan_emit_kernel(
        const int* __restrict__ deg, const int* __restrict__ pofs,
        int* __restrict__ row_ptr, float* __restrict__ norm) {
    __shared__ int s[256];
    int t = threadIdx.x;
    int base = blockIdx.x * SCAN_CHUNK;
    int i0 = 2 * t, i1 = 2 * t + 1;
    int d0 = (i0 < SCAN_CHUNK) ? deg[base + i0] : 0;
    int d1 = (i1 < SCAN_CHUNK) ? deg[base + i1] : 0;
    int p0 = (d0 + 7) & ~7, p1 = (d1 + 7) & ~7;
    s[t] = p0 + p1;
    __syncthreads();
    for (int off = 1; off < 256; off <<= 1) {
        int v = (t >= off) ? s[t - off] : 0;
        __syncthreads();
        s[t] += v;
        __syncthreads();
    }
    int p = s[t] - (p0 + p1) + pofs[blockIdx.x];
    if (i0 < SCAN_CHUNK) {
        row_ptr[base + i0] = p;
        norm[base + i0] = rsqrtf((float)max(d0, 1));
    }
    if (i1 < SCAN_CHUNK) {
        row_ptr[base + i1] = p + p0;
        norm[base + i1] = rsqrtf((float)max(d1, 1));
    }
}

// atomic-free scatter: position was fixed by the deg pass
__global__ void scatter_kernel(const int* __restrict__ src, const int* __restrict__ dst,
                               const int* __restrict__ slot,
                               const int* __restrict__ row_ptr,
                               int* __restrict__ es, int e) {
    int i = blockIdx.x * blockDim.x + threadIdx.x;
    if (i < e) es[row_ptr[dst[i]] + slot[i]] = src[i];
}

// pad slots -> the zero row (index N_NODES)
__global__ void pad_kernel(const int* __restrict__ deg, const int* __restrict__ row_ptr,
                           int* __restrict__ es, int n) {
    int i = blockIdx.x * blockDim.x + threadIdx.x;
    if (i < n) {
        int b = row_ptr[i] + deg[i];
        int e = row_ptr[i + 1];
        for (int s = b; s < e; ++s) es[s] = N_NODES;
    }
}

// W1 [100][256] fp32 -> W1p: MFMA B-frags, 16 n-tiles x 4 k-steps, K padded 128.
__global__ void pack_w1_kernel(const float* __restrict__ W1, __half* __restrict__ W1p) {
    int idx = blockIdx.x * blockDim.x + threadIdx.x;   // 32768 halfs
    if (idx >= 16 * 4 * 64 * 8) return;
    int j = idx & 7;
    int lane = (idx >> 3) & 63;
    int ks = (idx >> 9) & 3;
    int nt = idx >> 11;
    int k = ks * 32 + (lane >> 4) * 8 + j;
    int n = nt * 16 + (lane & 15);
    float v = (k < D_DATA) ? W1[(size_t)k * H_DIM + n] : 0.f;
    W1p[idx] = __float2half(v);
}

// W2 [256][47] fp32 -> W2p: 3 n-tiles x 8 k-steps, N padded 48.
__global__ void pack_w2_kernel(const float* __restrict__ W2, __half* __restrict__ W2p) {
    int idx = blockIdx.x * blockDim.x + threadIdx.x;   // 12288 halfs
    if (idx >= 3 * 8 * 64 * 8) return;
    int j = idx & 7;
    int lane = (idx >> 3) & 63;
    int ks = (idx >> 9) & 7;
    int nt = idx >> 12;
    int k = ks * 32 + (lane >> 4) * 8 + j;
    int n = nt * 16 + (lane & 15);
    float v = (n < N_CLS) ? W2[(size_t)k * N_CLS + n] : 0.f;
    W2p[idx] = __float2half(v);
}

// x (fp32, dense) -> xhat slabs = norm (.) x, 64-half (128 B) rows per slab;
// slab = blockIdx.y (feats 0..63 / 64..99+pad). Row N_NODES all zeros.
__global__ void convert_xhat_kernel(const float* __restrict__ x,
                                    const float* __restrict__ norm,
                                    __half2* __restrict__ xh) {
    int i = blockIdx.x * blockDim.x + threadIdx.x;   // slab-local half2 index
    if (i >= (N_NODES + 1) * (SH / 2)) return;
    int slab = blockIdx.y;
    int node = i >> 5;          // 32 half2 per slab row
    int c = i & 31;
    int f = slab * SH + 2 * c;
    float2 v = make_float2(0.f, 0.f);
    if (node < N_NODES && f <= D_DATA - 2) {
        float nn = norm[node];
        float2 xv = *(const float2*)(x + (size_t)node * D_DATA + f);
        v = make_float2(nn * xv.x, nn * xv.y);
    }
    xh[(size_t)slab * (SLAB_HALFS / 2) + i] = __float22half2_rn(v);
}

// zero the pad-gather rows (row N_NODES of both slabs of both ping-pong
// pairs) and the MLP tail rows (100000..100031 of the 128-stride buffer)
__global__ void zero_misc_kernel(__half2* __restrict__ a, __half2* __restrict__ b,
                                 __half2* __restrict__ h128) {
    int t = threadIdx.x;   // 256 threads, 1 block
    if (t < 32)        a[(size_t)N_NODES * 32 + t] = __half2();
    else if (t < 64)   a[SLAB_HALFS / 2 + (size_t)N_NODES * 32 + (t - 32)] = __half2();
    else if (t < 96)   b[(size_t)N_NODES * 32 + (t - 64)] = __half2();
    else if (t < 128)  b[SLAB_HALFS / 2 + (size_t)N_NODES * 32 + (t - 96)] = __half2();
    for (int i = t; i < 32 * (HS / 2); i += 256)
        h128[(size_t)N_NODES * (HS / 2) + i] = __half2();
}

// ---------------- propagation (slab-split, 2 nodes/wave, 8-edge batches) ----
// blockIdx.y = slab. Lane l = (g=l>>5, c=l&31): per gather instruction the
// two 32-lane groups read rows of edges 2t and 2t+1 (2 lines each -> 4 line
// requests/instr, the proven R14 TA shape). Per iteration: 8 gathers = 16
// edge-slots across nodes A,B. Cross-group shfl_xor(32) folds parities; the
// epilogue writes node A from group 0 lanes and node B from group 1 lanes.
// FINAL writes into the 128-stride MLP layout at col offset slab*64 (slab 1
// auto-zeroes cols 100..127) with exact fp32 teleport.

template <bool FINAL>
__global__ __launch_bounds__(256) void prop_half_kernel(
        const __half* __restrict__ hin,   // slab-pair base
        const __half* __restrict__ xh,    // slab-pair xhat (mid only)
        const float* __restrict__ xf,     // FINAL only: raw fp32 x
        const float* __restrict__ norm, const int* __restrict__ row_ptr,
        const int* __restrict__ es, __half* __restrict__ hout, int n_nodes) {
    int lane = threadIdx.x & 63;
    int g = lane >> 5;    // edge-parity group
    int c = lane & 31;    // half2 column within the 64-half slab row
    int slab = blockIdx.y;
    const __half* hin_s = hin + (size_t)slab * SLAB_HALFS;

    int wave = blockIdx.x * 4 + (threadIdx.x >> 6);
    int nA = __builtin_amdgcn_readfirstlane(wave * 2);
    if (nA >= n_nodes) return;
    int nB = nA + 1;
    int begA = __builtin_amdgcn_readfirstlane(row_ptr[nA]);
    int begB = __builtin_amdgcn_readfirstlane(row_ptr[nB]);
    int endB = __builtin_amdgcn_readfirstlane(row_ptr[nB + 1]);
    int nbA = (begB - begA) >> 3;   // 8-edge batches (padded deg % 8 == 0)
    int nbB = (endB - begB) >> 3;
    int mb = nbA > nbB ? nbA : nbB;

    float aAx = 0.f, aAy = 0.f, aBx = 0.f, aBy = 0.f;
    for (int it = 0; it < mb; ++it) {
        bool doA = it < nbA, doB = it < nbB;   // uniform
        int sA[8], sB[8];
        if (doA) {
            int e = begA + it * 8;
#pragma unroll
            for (int j = 0; j < 8; ++j) sA[j] = es[e + j];   // uniform -> s_load
        }
        if (doB) {
            int e = begB + it * 8;
#pragma unroll
            for (int j = 0; j < 8; ++j) sB[j] = es[e + j];
        }
        __half2 hvA[4], hvB[4];
        if (doA) {
#pragma unroll
            for (int t = 0; t < 4; ++t) {
                int row = g ? sA[2 * t + 1] : sA[2 * t];
                hvA[t] = ((const __half2*)(hin_s + (size_t)row * SH))[c];
            }
        }
        if (doB) {
#pragma unroll
            for (int t = 0; t < 4; ++t) {
                int row = g ? sB[2 * t + 1] : sB[2 * t];
                hvB[t] = ((const __half2*)(hin_s + (size_t)row * SH))[c];
            }
        }
        if (doA) {
            float2 v0 = __half22float2(hvA[0]), v1 = __half22float2(hvA[1]);
            float2 v2 = __half22float2(hvA[2]), v3 = __half22float2(hvA[3]);
            aAx += (v0.x + v1.x) + (v2.x + v3.x);
            aAy += (v0.y + v1.y) + (v2.y + v3.y);
        }
        if (doB) {
            float2 v0 = __half22float2(hvB[0]), v1 = __half22float2(hvB[1]);
            float2 v2 = __half22float2(hvB[2]), v3 = __half22float2(hvB[3]);
            aBx += (v0.x + v1.x) + (v2.x + v3.x);
            aBy += (v0.y + v1.y) + (v2.y + v3.y);
        }
    }
    // fold the two edge-parity groups (lane l and l^32 share column c)
    aAx += __shfl_xor(aAx, 32, 64);
    aAy += __shfl_xor(aAy, 32, 64);
    aBx += __shfl_xor(aBx, 32, 64);
    aBy += __shfl_xor(aBy, 32, 64);

    int node = g ? nB : nA;
    float sx = g ? aBx : aAx;
    float sy = g ? aBy : aAy;
    if (!FINAL) {
        float nn = norm[node];
        float cf = (1.0f - ALPHA) * nn * nn;
        float2 t = __half22float2(
            ((const __half2*)(xh + (size_t)slab * SLAB_HALFS + (size_t)node * SH))[c]);
        float2 o = make_float2(cf * sx + ALPHA * t.x, cf * sy + ALPHA * t.y);
        ((__half2*)(hout + (size_t)slab * SLAB_HALFS + (size_t)node * SH))[c] =
            __float22half2_rn(o);
    } else {
        float cf = (1.0f - ALPHA) * norm[node];
        int f = slab * SH + 2 * c;
        float2 xv = make_float2(0.f, 0.f);
        if (f <= D_DATA - 2)
            xv = *(const float2*)(xf + (size_t)node * D_DATA + f);
        float2 o = make_float2(cf * sx + ALPHA * xv.x, cf * sy + ALPHA * xv.y);
        ((__half2*)(hout + (size_t)node * HS + slab * SH))[c] = __float22half2_rn(o);
    }
}

// ---------------- MFMA MLP (unchanged from R9-R15) ----------------

#define ZP 264

__global__ __launch_bounds__(256, 4) void mlp_mfma_kernel(
        const __half* __restrict__ h16,
        const __half* __restrict__ W1p, const float* __restrict__ b1,
        const __half* __restrict__ W2p, const float* __restrict__ b2,
        float* __restrict__ out, int n_nodes) {
    __shared__ _Float16 zs[MB][ZP];   // 33 KB -> 4 blocks/CU
    int tid = threadIdx.x;
    int lane = tid & 63;
    int w = tid >> 6;
    int q = lane >> 4;
    int r = lane & 15;
    int node0 = blockIdx.x * MB + w * 16;

    half8_t a1[4];
#pragma unroll
    for (int ks = 0; ks < 4; ++ks)
        a1[ks] = *(const half8_t*)(h16 + (size_t)(node0 + r) * HS + ks * 32 + q * 8);

    const half8_t* w1f = (const half8_t*)W1p;
#pragma unroll 4
    for (int nt = 0; nt < 16; ++nt) {
        floatx4 acc = {0.f, 0.f, 0.f, 0.f};
#pragma unroll
        for (int ks = 0; ks < 4; ++ks) {
            half8_t b = w1f[(nt * 4 + ks) * 64 + lane];
            acc = __builtin_amdgcn_mfma_f32_16x16x32_f16(a1[ks], b, acc, 0, 0, 0);
        }
        float bb = b1[nt * 16 + r];
#pragma unroll
        for (int reg = 0; reg < 4; ++reg) {
            float zv = fmaxf(acc[reg] + bb, 0.f);
            zs[w * 16 + q * 4 + reg][nt * 16 + r] = (_Float16)zv;
        }
    }

    half8_t a2[8];
#pragma unroll
    for (int ks = 0; ks < 8; ++ks)
        a2[ks] = *(const half8_t*)&zs[w * 16 + r][ks * 32 + q * 8];

    const half8_t* w2f = (const half8_t*)W2p;
#pragma unroll
    for (int nt = 0; nt < 3; ++nt) {
        floatx4 acc = {0.f, 0.f, 0.f, 0.f};
#pragma unroll
        for (int ks = 0; ks < 8; ++ks) {
            half8_t b = w2f[(nt * 8 + ks) * 64 + lane];
            acc = __builtin_amdgcn_mfma_f32_16x16x32_f16(a2[ks], b, acc, 0, 0, 0);
        }
        int cix = nt * 16 + r;
        if (cix < N_CLS) {
            float bb = b2[cix];
#pragma unroll
            for (int reg = 0; reg < 4; ++reg) {
                int node = node0 + q * 4 + reg;
                if (node < n_nodes)
                    out[(size_t)node * N_CLS + cix] = acc[reg] + bb;
            }
        }
    }
}

// ---------------- launch ----------------

static inline size_t align_up(size_t v, size_t a) { return (v + a - 1) & ~(a - 1); }

extern "C" void kernel_launch(void* const* d_in, const int* in_sizes, int n_in,
                              void* d_out, int out_size, void* d_ws, size_t ws_size,
                              hipStream_t stream) {
    const float* x   = (const float*)d_in[0];
    const int*   src = (const int*)d_in[1];
    const int*   dst = (const int*)d_in[2];
    const float* W1  = (const float*)d_in[3];
    const float* b1  = (const float*)d_in[4];
    const float* W2  = (const float*)d_in[5];
    const float* b2  = (const float*)d_in[6];
    float* out = (float*)d_out;

    char* p = (char*)d_ws;
    size_t off = 0;
    int* deg = (int*)(p + off);           off = align_up(off + N_NODES * 4, 256);
    int* row_ptr = (int*)(p + off);       off = align_up(off + (N_NODES + 1) * 4, 256);
    int* slot = (int*)(p + off);          off = align_up(off + (size_t)N_EDGES * 4, 256);
    float* norm = (float*)(p + off);      off = align_up(off + N_NODES * 4, 256);
    int* partials = (int*)(p + off);      off = align_up(off + SCAN_NB * 4, 256);
    int* pofs = (int*)(p + off);          off = align_up(off + SCAN_NB * 4, 256);
    __half* W1p = (__half*)(p + off);     off = align_up(off + 16 * 4 * 64 * 8 * 2, 256);
    __half* W2p = (__half*)(p + off);     off = align_up(off + 3 * 8 * 64 * 8 * 2, 256);
    int* es = (int*)(p + off);            off = align_up(off + (size_t)EW_CAP * 4, 256);
    __half* xhp = (__half*)(p + off);     off = align_up(off + 2 * SLAB_HALFS * 2, 256);
    __half* hAA = (__half*)(p + off);     off = align_up(off + 2 * SLAB_HALFS * 2, 256);
    __half* hBB = (__half*)(p + off);     off = align_up(off + 2 * SLAB_HALFS * 2, 256);
    __half* h16 = (__half*)(p + off);     off = align_up(off + (size_t)N_PAD * HS * 2, 256);
    (void)ws_size;

    hipMemsetAsync(deg, 0, N_NODES * 4, stream);

    int eb = (N_EDGES + 255) / 256;
    deg_kernel<<<eb, 256, 0, stream>>>(dst, deg, slot, N_EDGES);
    scan_partial_kernel<<<SCAN_NB, 256, 0, stream>>>(deg, partials);
    scan_top_kernel<<<1, 256, 0, stream>>>(partials, pofs, row_ptr);
    scan_emit_kernel<<<SCAN_NB, 256, 0, stream>>>(deg, pofs, row_ptr, norm);
    scatter_kernel<<<eb, 256, 0, stream>>>(src, dst, slot, row_ptr, es, N_EDGES);
    pad_kernel<<<(N_NODES + 255) / 256, 256, 0, stream>>>(deg, row_ptr, es, N_NODES);
    pack_w1_kernel<<<128, 256, 0, stream>>>(W1, W1p);
    pack_w2_kernel<<<48, 256, 0, stream>>>(W2, W2p);

    int nch = (N_NODES + 1) * (SH / 2);   // half2 per slab, incl. zero row
    convert_xhat_kernel<<<dim3((nch + 255) / 256, 2), 256, 0, stream>>>(
        x, norm, (__half2*)xhp);
    zero_misc_kernel<<<1, 256, 0, stream>>>((__half2*)hAA, (__half2*)hBB, (__half2*)h16);

    dim3 pg((N_NODES / 2) / 4, 2);   // 12500 blocks x 2 slabs
    // k=0: xhat -> AA; k=1..8 ping-pong (odd->BB, even->AA); k=9 final -> h16
    prop_half_kernel<false><<<pg, 256, 0, stream>>>(xhp, xhp, nullptr, norm, row_ptr, es, hAA, N_NODES);
    const __half* hin = hAA;
    for (int k = 1; k < K_STEPS - 1; ++k) {
        __half* ho = (k & 1) ? hBB : hAA;
        prop_half_kernel<false><<<pg, 256, 0, stream>>>(hin, xhp, nullptr, norm, row_ptr, es, ho, N_NODES);
        hin = ho;
    }
    prop_half_kernel<true><<<pg, 256, 0, stream>>>(hin, nullptr, x, norm, row_ptr, es, h16, N_NODES);

    int mbk = (N_NODES + MB - 1) / MB;
    mlp_mfma_kernel<<<mbk, 256, 0, stream>>>(h16, W1p, b1, W2p, b2, out, N_NODES);
}

// Round 6
// 543.241 us; speedup vs baseline: 1.7849x; 1.7849x over previous
//
#include <hip/hip_runtime.h>
#include <hip/hip_fp16.h>

// APPNP: K steps of D^{-1/2} A D^{-1/2} propagation + teleport, then MFMA MLP.
// R17: R14 base (proven 2-nodes/wave, 8-edge batches, 1 coalesced row per
// gather instruction) + L2-pollution control: the zero-reuse streams (xhat
// teleport reads, h_out writes) use non-temporal loads/stores so they do not
// evict gather rows from the 4MB/XCD L2 (gathers keep normal caching -> the
// ~40% retouch hit rate can rise). Launch trims: pad slots written by
// scan_emit (disjoint from scatter's slots), zero-row init folded into
// convert_xhat. R16's slab split is reverted (LDS-shuffle bank conflicts +
// concurrent slabs defeated the footprint halving).

#define N_NODES 100000
#define N_PAD   100032   // rows allocated (zero row at N_NODES + MLP slack)
#define N_EDGES 800000
#define D_DATA  100
#define H_DIM   256
#define N_CLS   47
#define K_STEPS 10
#define ALPHA   0.1f
#define HS      128      // fp16 row stride (halfs); cols 100..127 are zero
#define MB      64       // nodes per MLP block

#define SCAN_NB    200
#define SCAN_CHUNK 500   // 200*500 == N_NODES
#define EW_CAP (N_EDGES + 7 * N_NODES)   // degrees padded to multiple of 8

typedef _Float16 half8_t __attribute__((ext_vector_type(8)));
typedef float floatx4 __attribute__((ext_vector_type(4)));

// ---------------- CSR build ----------------

// histogram + per-edge slot (within-dst rank; order irrelevant, weights are 1)
__global__ void deg_kernel(const int* __restrict__ dst, int* __restrict__ deg,
                           int* __restrict__ slot, int e) {
    int i = blockIdx.x * blockDim.x + threadIdx.x;
    if (i < e) slot[i] = atomicAdd(&deg[dst[i]], 1);
}

__global__ __launch_bounds__(256) void scan_partial_kernel(
        const int* __restrict__ deg, int* __restrict__ partials) {
    __shared__ int red[256];
    int t = threadIdx.x;
    int base = blockIdx.x * SCAN_CHUNK;
    int s = 0;
    int i0 = 2 * t, i1 = 2 * t + 1;
    if (i0 < SCAN_CHUNK) s += (deg[base + i0] + 7) & ~7;
    if (i1 < SCAN_CHUNK) s += (deg[base + i1] + 7) & ~7;
    red[t] = s;
    __syncthreads();
    for (int off = 128; off > 0; off >>= 1) {
        if (t < off) red[t] += red[t + off];
        __syncthreads();
    }
    if (t == 0) partials[blockIdx.x] = red[0];
}

__global__ __launch_bounds__(256) void scan_top_kernel(
        const int* __restrict__ partials, int* __restrict__ pofs,
        int* __restrict__ row_ptr) {
    __shared__ int s[256];
    int t = threadIdx.x;
    s[t] = (t < SCAN_NB) ? partials[t] : 0;
    __syncthreads();
    for (int off = 1; off < 256; off <<= 1) {
        int v = (t >= off) ? s[t - off] : 0;
        __syncthreads();
        s[t] += v;
        __syncthreads();
    }
    if (t < SCAN_NB) pofs[t] = s[t] - partials[t];
    if (t == SCAN_NB - 1) row_ptr[N_NODES] = s[t];   // padded total
}

// emits row_ptr + norm AND fills the pad slots of es (disjoint from the real
// slots scatter_kernel writes later, so ordering across kernels is free)
__global__ __launch_bounds__(256) void scan_emit_kernel(
        const int* __restrict__ deg, const int* __restrict__ pofs,
        int* __restrict__ row_ptr, float* __restrict__ norm,
        int* __restrict__ es) {
    __shared__ int s[256];
    int t = threadIdx.x;
    int base = blockIdx.x * SCAN_CHUNK;
    int i0 = 2 * t, i1 = 2 * t + 1;
    int d0 = (i0 < SCAN_CHUNK) ? deg[base + i0] : 0;
    int d1 = (i1 < SCAN_CHUNK) ? deg[base + i1] : 0;
    int p0 = (d0 + 7) & ~7, p1 = (d1 + 7) & ~7;
    s[t] = p0 + p1;
    __syncthreads();
    for (int off = 1; off < 256; off <<= 1) {
        int v = (t >= off) ? s[t - off] : 0;
        __syncthreads();
        s[t] += v;
        __syncthreads();
    }
    int p = s[t] - (p0 + p1) + pofs[blockIdx.x];
    if (i0 < SCAN_CHUNK) {
        row_ptr[base + i0] = p;
        norm[base + i0] = rsqrtf((float)max(d0, 1));
        for (int q = d0; q < p0; ++q) es[p + q] = N_NODES;   // pad -> zero row
    }
    if (i1 < SCAN_CHUNK) {
        row_ptr[base + i1] = p + p0;
        norm[base + i1] = rsqrtf((float)max(d1, 1));
        for (int q = d1; q < p1; ++q) es[p + p0 + q] = N_NODES;
    }
}

// atomic-free scatter: position was fixed by the deg pass
__global__ void scatter_kernel(const int* __restrict__ src, const int* __restrict__ dst,
                               const int* __restrict__ slot,
                               const int* __restrict__ row_ptr,
                               int* __restrict__ es, int e) {
    int i = blockIdx.x * blockDim.x + threadIdx.x;
    if (i < e) es[row_ptr[dst[i]] + slot[i]] = src[i];
}

// W1 [100][256] fp32 -> W1p: MFMA B-frags, 16 n-tiles x 4 k-steps, K padded 128.
__global__ void pack_w1_kernel(const float* __restrict__ W1, __half* __restrict__ W1p) {
    int idx = blockIdx.x * blockDim.x + threadIdx.x;   // 32768 halfs
    if (idx >= 16 * 4 * 64 * 8) return;
    int j = idx & 7;
    int lane = (idx >> 3) & 63;
    int ks = (idx >> 9) & 3;
    int nt = idx >> 11;
    int k = ks * 32 + (lane >> 4) * 8 + j;
    int n = nt * 16 + (lane & 15);
    float v = (k < D_DATA) ? W1[(size_t)k * H_DIM + n] : 0.f;
    W1p[idx] = __float2half(v);
}

// W2 [256][47] fp32 -> W2p: 3 n-tiles x 8 k-steps, N padded 48.
__global__ void pack_w2_kernel(const float* __restrict__ W2, __half* __restrict__ W2p) {
    int idx = blockIdx.x * blockDim.x + threadIdx.x;   // 12288 halfs
    if (idx >= 3 * 8 * 64 * 8) return;
    int j = idx & 7;
    int lane = (idx >> 3) & 63;
    int ks = (idx >> 9) & 7;
    int nt = idx >> 12;
    int k = ks * 32 + (lane >> 4) * 8 + j;
    int n = nt * 16 + (lane & 15);
    float v = (n < N_CLS) ? W2[(size_t)k * N_CLS + n] : 0.f;
    W2p[idx] = __float2half(v);
}

// x (fp32, dense) -> xhat16 = norm (.) x (fp16, stride 128, zero pads);
// row N_NODES is all zeros; also zero-inits row N_NODES of h16A/h16B
// (gather target of CSR pad edges) -> no separate zero_rows launch.
__global__ void convert_xhat_kernel(const float* __restrict__ x,
                                    const float* __restrict__ norm,
                                    __half2* __restrict__ xh,
                                    __half2* __restrict__ hA,
                                    __half2* __restrict__ hB, int n_half2) {
    int i = blockIdx.x * blockDim.x + threadIdx.x;
    if (i < n_half2) {
        int node = i >> 6;          // 64 half2 per row
        int c2 = i & 63;
        float2 v = make_float2(0.f, 0.f);
        if (node < N_NODES && c2 < D_DATA / 2) {
            float nn = norm[node];
            const float2* r = (const float2*)(x + (size_t)node * D_DATA);
            float2 xv = r[c2];
            v = make_float2(nn * xv.x, nn * xv.y);
        }
        xh[i] = __float22half2_rn(v);
        if (node == N_NODES) { hA[i] = __half2(); hB[i] = __half2(); }
    }
}

// ---------------- propagation (h_hat space, 2 nodes per wave, 8-edge batches)
// Lane l holds half2 l of each 256B row; one gather instruction = one row
// (fully coalesced 4-line request), NORMAL caching (L2 retouch reuse).
// Streams with zero reuse -- the xhat teleport read and the h_out write --
// are non-temporal so they don't evict gather rows from L2.

static __device__ __forceinline__ __half2 nt_load_h2(const __half* p, int lane) {
    uint32_t b = __builtin_nontemporal_load((const uint32_t*)p + lane);
    return *reinterpret_cast<__half2*>(&b);
}
static __device__ __forceinline__ void nt_store_h2(__half* p, int lane, __half2 v) {
    __builtin_nontemporal_store(*reinterpret_cast<uint32_t*>(&v), (uint32_t*)p + lane);
}

template <bool FINAL>
__global__ __launch_bounds__(256) void prop_kernel(
        const __half* __restrict__ hin, const __half* __restrict__ xhat,
        const float* __restrict__ xf,   // FINAL only: raw fp32 x
        const float* __restrict__ norm, const int* __restrict__ row_ptr,
        const int* __restrict__ es, __half* __restrict__ hout, int n_nodes) {
    int lane = threadIdx.x & 63;
    int wave = blockIdx.x * 4 + (threadIdx.x >> 6);
    int nA = __builtin_amdgcn_readfirstlane(wave * 2);
    if (nA >= n_nodes) return;
    int nB = nA + 1;
    int begA = __builtin_amdgcn_readfirstlane(row_ptr[nA]);
    int begB = __builtin_amdgcn_readfirstlane(row_ptr[nB]);
    int endB = __builtin_amdgcn_readfirstlane(row_ptr[nB + 1]);
    int nbA = (begB - begA) >> 3;   // 8-edge batches (padded deg % 8 == 0)
    int nbB = (endB - begB) >> 3;
    int mb = nbA > nbB ? nbA : nbB;

    float a0x = 0.f, a0y = 0.f, a1x = 0.f, a1y = 0.f;   // node A, 2 chains
    float b0x = 0.f, b0y = 0.f, b1x = 0.f, b1y = 0.f;   // node B, 2 chains
    for (int it = 0; it < mb; ++it) {
        bool doA = it < nbA, doB = it < nbB;   // uniform
        int sA[8], sB[8];
        if (doA) {
            int e = begA + it * 8;
#pragma unroll
            for (int j = 0; j < 8; ++j) sA[j] = es[e + j];   // uniform -> s_load
        }
        if (doB) {
            int e = begB + it * 8;
#pragma unroll
            for (int j = 0; j < 8; ++j) sB[j] = es[e + j];
        }
        __half2 hvA[8], hvB[8];
        if (doA) {
#pragma unroll
            for (int j = 0; j < 8; ++j)
                hvA[j] = ((const __half2*)(hin + (size_t)sA[j] * HS))[lane];
        }
        if (doB) {
#pragma unroll
            for (int j = 0; j < 8; ++j)
                hvB[j] = ((const __half2*)(hin + (size_t)sB[j] * HS))[lane];
        }
        if (doA) {
            float2 v0 = __half22float2(hvA[0]), v1 = __half22float2(hvA[1]);
            float2 v2 = __half22float2(hvA[2]), v3 = __half22float2(hvA[3]);
            float2 v4 = __half22float2(hvA[4]), v5 = __half22float2(hvA[5]);
            float2 v6 = __half22float2(hvA[6]), v7 = __half22float2(hvA[7]);
            a0x += (v0.x + v2.x) + (v4.x + v6.x);
            a0y += (v0.y + v2.y) + (v4.y + v6.y);
            a1x += (v1.x + v3.x) + (v5.x + v7.x);
            a1y += (v1.y + v3.y) + (v5.y + v7.y);
        }
        if (doB) {
            float2 v0 = __half22float2(hvB[0]), v1 = __half22float2(hvB[1]);
            float2 v2 = __half22float2(hvB[2]), v3 = __half22float2(hvB[3]);
            float2 v4 = __half22float2(hvB[4]), v5 = __half22float2(hvB[5]);
            float2 v6 = __half22float2(hvB[6]), v7 = __half22float2(hvB[7]);
            b0x += (v0.x + v2.x) + (v4.x + v6.x);
            b0y += (v0.y + v2.y) + (v4.y + v6.y);
            b1x += (v1.x + v3.x) + (v5.x + v7.x);
            b1y += (v1.y + v3.y) + (v5.y + v7.y);
        }
    }
    {   // node A epilogue
        if (!FINAL) {
            float nn = norm[nA];
            float c = (1.0f - ALPHA) * nn * nn;
            float2 t = __half22float2(nt_load_h2(xhat + (size_t)nA * HS, lane));
            float2 o = make_float2(c * (a0x + a1x) + ALPHA * t.x,
                                   c * (a0y + a1y) + ALPHA * t.y);
            nt_store_h2(hout + (size_t)nA * HS, lane, __float22half2_rn(o));
        } else {
            float c = (1.0f - ALPHA) * norm[nA];
            float2 xv = make_float2(0.f, 0.f);
            if (lane < D_DATA / 2)
                xv = ((const float2*)(xf + (size_t)nA * D_DATA))[lane];
            float2 o = make_float2(c * (a0x + a1x) + ALPHA * xv.x,
                                   c * (a0y + a1y) + ALPHA * xv.y);
            nt_store_h2(hout + (size_t)nA * HS, lane, __float22half2_rn(o));
        }
    }
    {   // node B epilogue
        if (!FINAL) {
            float nn = norm[nB];
            float c = (1.0f - ALPHA) * nn * nn;
            float2 t = __half22float2(nt_load_h2(xhat + (size_t)nB * HS, lane));
            float2 o = make_float2(c * (b0x + b1x) + ALPHA * t.x,
                                   c * (b0y + b1y) + ALPHA * t.y);
            nt_store_h2(hout + (size_t)nB * HS, lane, __float22half2_rn(o));
        } else {
            float c = (1.0f - ALPHA) * norm[nB];
            float2 xv = make_float2(0.f, 0.f);
            if (lane < D_DATA / 2)
                xv = ((const float2*)(xf + (size_t)nB * D_DATA))[lane];
            float2 o = make_float2(c * (b0x + b1x) + ALPHA * xv.x,
                                   c * (b0y + b1y) + ALPHA * xv.y);
            nt_store_h2(hout + (size_t)nB * HS, lane, __float22half2_rn(o));
        }
    }
}

// ---------------- MFMA MLP (unchanged from R9-R14) ----------------

#define ZP 264

__global__ __launch_bounds__(256, 4) void mlp_mfma_kernel(
        const __half* __restrict__ h16,
        const __half* __restrict__ W1p, const float* __restrict__ b1,
        const __half* __restrict__ W2p, const float* __restrict__ b2,
        float* __restrict__ out, int n_nodes) {
    __shared__ _Float16 zs[MB][ZP];   // 33 KB -> 4 blocks/CU
    int tid = threadIdx.x;
    int lane = tid & 63;
    int w = tid >> 6;
    int q = lane >> 4;
    int r = lane & 15;
    int node0 = blockIdx.x * MB + w * 16;

    half8_t a1[4];
#pragma unroll
    for (int ks = 0; ks < 4; ++ks)
        a1[ks] = *(const half8_t*)(h16 + (size_t)(node0 + r) * HS + ks * 32 + q * 8);

    const half8_t* w1f = (const half8_t*)W1p;
#pragma unroll 4
    for (int nt = 0; nt < 16; ++nt) {
        floatx4 acc = {0.f, 0.f, 0.f, 0.f};
#pragma unroll
        for (int ks = 0; ks < 4; ++ks) {
            half8_t b = w1f[(nt * 4 + ks) * 64 + lane];
            acc = __builtin_amdgcn_mfma_f32_16x16x32_f16(a1[ks], b, acc, 0, 0, 0);
        }
        float bb = b1[nt * 16 + r];
#pragma unroll
        for (int reg = 0; reg < 4; ++reg) {
            float zv = fmaxf(acc[reg] + bb, 0.f);
            zs[w * 16 + q * 4 + reg][nt * 16 + r] = (_Float16)zv;
        }
    }

    half8_t a2[8];
#pragma unroll
    for (int ks = 0; ks < 8; ++ks)
        a2[ks] = *(const half8_t*)&zs[w * 16 + r][ks * 32 + q * 8];

    const half8_t* w2f = (const half8_t*)W2p;
#pragma unroll
    for (int nt = 0; nt < 3; ++nt) {
        floatx4 acc = {0.f, 0.f, 0.f, 0.f};
#pragma unroll
        for (int ks = 0; ks < 8; ++ks) {
            half8_t b = w2f[(nt * 8 + ks) * 64 + lane];
            acc = __builtin_amdgcn_mfma_f32_16x16x32_f16(a2[ks], b, acc, 0, 0, 0);
        }
        int cix = nt * 16 + r;
        if (cix < N_CLS) {
            float bb = b2[cix];
#pragma unroll
            for (int reg = 0; reg < 4; ++reg) {
                int node = node0 + q * 4 + reg;
                if (node < n_nodes)
                    out[(size_t)node * N_CLS + cix] = acc[reg] + bb;
            }
        }
    }
}

// ---------------- launch ----------------

static inline size_t align_up(size_t v, size_t a) { return (v + a - 1) & ~(a - 1); }

extern "C" void kernel_launch(void* const* d_in, const int* in_sizes, int n_in,
                              void* d_out, int out_size, void* d_ws, size_t ws_size,
                              hipStream_t stream) {
    const float* x   = (const float*)d_in[0];
    const int*   src = (const int*)d_in[1];
    const int*   dst = (const int*)d_in[2];
    const float* W1  = (const float*)d_in[3];
    const float* b1  = (const float*)d_in[4];
    const float* W2  = (const float*)d_in[5];
    const float* b2  = (const float*)d_in[6];
    float* out = (float*)d_out;

    char* p = (char*)d_ws;
    size_t off = 0;
    int* deg = (int*)(p + off);           off = align_up(off + N_NODES * 4, 256);
    int* row_ptr = (int*)(p + off);       off = align_up(off + (N_NODES + 1) * 4, 256);
    int* slot = (int*)(p + off);          off = align_up(off + (size_t)N_EDGES * 4, 256);
    float* norm = (float*)(p + off);      off = align_up(off + N_NODES * 4, 256);
    int* partials = (int*)(p + off);      off = align_up(off + SCAN_NB * 4, 256);
    int* pofs = (int*)(p + off);          off = align_up(off + SCAN_NB * 4, 256);
    __half* W1p = (__half*)(p + off);     off = align_up(off + 16 * 4 * 64 * 8 * 2, 256);
    __half* W2p = (__half*)(p + off);     off = align_up(off + 3 * 8 * 64 * 8 * 2, 256);
    int* es = (int*)(p + off);            off = align_up(off + (size_t)EW_CAP * 4, 256);
    __half* xhat = (__half*)(p + off);    off = align_up(off + (size_t)N_PAD * HS * 2, 256);
    __half* h16A = (__half*)(p + off);    off = align_up(off + (size_t)N_PAD * HS * 2, 256);
    __half* h16B = (__half*)(p + off);    off = align_up(off + (size_t)N_PAD * HS * 2, 256);
    (void)ws_size;

    hipMemsetAsync(deg, 0, N_NODES * 4, stream);

    int eb = (N_EDGES + 255) / 256;
    deg_kernel<<<eb, 256, 0, stream>>>(dst, deg, slot, N_EDGES);
    scan_partial_kernel<<<SCAN_NB, 256, 0, stream>>>(deg, partials);
    scan_top_kernel<<<1, 256, 0, stream>>>(partials, pofs, row_ptr);
    scan_emit_kernel<<<SCAN_NB, 256, 0, stream>>>(deg, pofs, row_ptr, norm, es);
    scatter_kernel<<<eb, 256, 0, stream>>>(src, dst, slot, row_ptr, es, N_EDGES);
    pack_w1_kernel<<<128, 256, 0, stream>>>(W1, W1p);
    pack_w2_kernel<<<48, 256, 0, stream>>>(W2, W2p);

    int nh2 = (N_NODES + 1) * (HS / 2);   // includes the zero row
    convert_xhat_kernel<<<(nh2 + 255) / 256, 256, 0, stream>>>(
        x, norm, (__half2*)xhat, (__half2*)h16A, (__half2*)h16B, nh2);

    int pb = (N_NODES / 2) / 4;   // 50000 node-pairs, 4 waves per block
    // k=0: xhat -> A; k=1..8 ping-pong (odd->B, even->A); k=9 final: A -> B
    prop_kernel<false><<<pb, 256, 0, stream>>>(xhat, xhat, nullptr, norm, row_ptr, es, h16A, N_NODES);
    const __half* hin = h16A;
    for (int k = 1; k < K_STEPS - 1; ++k) {
        __half* ho = (k & 1) ? h16B : h16A;
        prop_kernel<false><<<pb, 256, 0, stream>>>(hin, xhat, nullptr, norm, row_ptr, es, ho, N_NODES);
        hin = ho;
    }
    prop_kernel<true><<<pb, 256, 0, stream>>>(hin, nullptr, x, norm, row_ptr, es, h16B, N_NODES);

    int mbk = (N_NODES + MB - 1) / MB;
    mlp_mfma_kernel<<<mbk, 256, 0, stream>>>(h16B, W1p, b1, W2p, b2, out, N_NODES);
}